// Round 11
// baseline (164.792 us; speedup 1.0000x reference)
//
#include <hip/hip_runtime.h>

// Reference collapses: softmax row-sums are exactly 1, and einsum 'bqk,bvd->bqd'
// contracts k and v independently, so out[b,q,d] = sum_n v[b,n,d] (q-independent).
//   pbg[b,g,ch] = inv_{b,g}*sum_{n in g} gamma[n]*x[b,ch,n] + cshare_{b,g}  (K1)
//   colsum[b,ch] = sum_g pbg[b,g,ch]        (reduced inside K2)
//   S[b,d]       = dot(Wv[d,:], colsum[b,:]) + 1024*bv[d]                  (K2)
//   out[b,d,:]   = dot(Wo[d,:], S[b,:]) + bo[d]  broadcast over hw         (K3)
// Wq/bq/Wk/bk are provably dead (softmax row-sum == 1).
//
// Round 11 = round 10 with ONE variable reverted: K3 uses plain float4
// stores again (nontemporal stores are the prime suspect for the 158->165
// regression — nt bypasses L2/L3 allocation and changes the TCC write path;
// the harness's own fills stream through the caches at 6.4 TB/s). Everything
// else identical to round 10: atomic-free, memset-free, 3 dispatches.

#define BATCH 16
#define CH    1024
#define NHW   1024
#define G     32
#define NPG   32
#define EPG   (NPG*CH)
#define EPSV  1e-5f

// ---- K1: GN partials; block (b,g) owns group (b,g); plain stores ----
__global__ __launch_bounds__(1024, 8) void k1_partials(
    const float* __restrict__ x, const float* __restrict__ gamma,
    const float* __restrict__ beta, float* __restrict__ pbg)
{
    const int blk  = blockIdx.x;
    const int t    = threadIdx.x;
    const int lane = t & 63, wave = t >> 6;   // 16 waves
    const int b    = blk >> 5, g = blk & 31;
    const int n4   = t & 7;                   // which float4 of the group's 32 n's
    const int c0   = t >> 3;                  // starting channel 0..127

    __shared__ float pch[CH];                 // gamma-weighted per-channel partials
    __shared__ float r1[16], r2[16], rb[16];

    const float4* xg = reinterpret_cast<const float4*>(x + (size_t)b * (CH * NHW) + g * NPG);
    const float4  gm = reinterpret_cast<const float4*>(gamma + g * NPG)[n4];

    float4 vb[8];
    #pragma unroll
    for (int k = 0; k < 8; k++)               // 8 independent loads in flight
        vb[k] = xg[(c0 + k * 128) * (NHW / 4) + n4];

    float s1 = 0.f, s2 = 0.f;
    #pragma unroll
    for (int k = 0; k < 8; k++) {
        const float4 v = vb[k];
        const int ch = c0 + k * 128;
        s1 += v.x + v.y + v.z + v.w;
        s2 += v.x * v.x + v.y * v.y + v.z * v.z + v.w * v.w;
        float p = v.x * gm.x + v.y * gm.y + v.z * gm.z + v.w * gm.w;
        p += __shfl_xor(p, 1);
        p += __shfl_xor(p, 2);
        p += __shfl_xor(p, 4);
        if (n4 == 0) pch[ch] = p;             // one writer per 8-lane cluster
    }
    float bsum = beta[t];                     // 1024 threads cover beta exactly
    #pragma unroll
    for (int m = 1; m < 64; m <<= 1) {
        s1 += __shfl_xor(s1, m); s2 += __shfl_xor(s2, m); bsum += __shfl_xor(bsum, m);
    }
    if (lane == 0) { r1[wave] = s1; r2[wave] = s2; rb[wave] = bsum; }
    __syncthreads();

    float S1 = 0.f, S2 = 0.f, SB = 0.f;
    #pragma unroll
    for (int w = 0; w < 16; w++) { S1 += r1[w]; S2 += r2[w]; SB += rb[w]; }
    const float mean = S1 * (1.f / EPG);
    const float var  = S2 * (1.f / EPG) - mean * mean;
    const float inv  = rsqrtf(var + EPSV);
    float sg = gm.x + gm.y + gm.z + gm.w;     // this group's 32 gammas
    sg += __shfl_xor(sg, 1);
    sg += __shfl_xor(sg, 2);
    sg += __shfl_xor(sg, 4);
    const float cshare = SB * (1.f / 32.f) - inv * mean * sg;

    // Plain coalesced store (4 KB/block). Sum over the 32 g-blocks of batch b
    // (done in K2) reproduces the atomics version exactly.
    pbg[(size_t)blk * CH + t] = inv * pch[t] + cshare;
}

// ---- K2: reduce partials -> colsum (LDS) -> S rows ----
// 128 blocks = (b, s8): reduce batch b's 32 partial rows (128 KB, coalesced,
// L2/L3-resident), then compute rows d = s8*128 .. s8*128+127 (8 per wave).
__global__ __launch_bounds__(1024, 8) void k2_reduce_matvec(
    const float* __restrict__ pbg, const float* __restrict__ Wv,
    const float* __restrict__ bv, float* __restrict__ S)
{
    const int blk = blockIdx.x, t = threadIdx.x;
    const int lane = t & 63, wave = t >> 6;   // 16 waves
    const int b = blk >> 3, s8 = blk & 7;

    __shared__ float cs[CH];
    float acc = 0.f;
    #pragma unroll
    for (int g = 0; g < G; ++g)               // 32 coalesced 4-KB row reads
        acc += pbg[((size_t)b * G + g) * CH + t];
    cs[t] = acc;                              // colsum[b, t]
    __syncthreads();

    const float4* cs4 = reinterpret_cast<const float4*>(cs);
    const int d0 = s8 * 128 + wave * 8;
    #pragma unroll
    for (int j = 0; j < 8; j++) {
        const int d = d0 + j;
        const float4* wrow = reinterpret_cast<const float4*>(Wv + (size_t)d * CH);
        float a = 0.f;
        #pragma unroll
        for (int i = 0; i < 4; i++) {
            int e4 = i * 64 + lane;
            float4 w = wrow[e4];
            float4 c = cs4[e4];
            a += w.x * c.x + w.y * c.y + w.z * c.z + w.w * c.w;
        }
        #pragma unroll
        for (int m = 1; m < 64; m <<= 1) a += __shfl_xor(a, m);
        if (lane == 0) S[b * CH + d] = a + (float)NHW * bv[d];
    }
}

// ---- K3: out[b,d,:] = dot(Wo[d,:], S[b,:]) + bo[d], bcast over 1024 hw ----
// 512 blocks (b, slab) x 16 waves; wave computes 2 rows; S[b,:] staged in LDS.
// Plain cached float4 stores (nt-store reverted — R10 regression suspect).
__global__ __launch_bounds__(1024, 8) void k3_out(
    const float* __restrict__ Wo, const float* __restrict__ bo,
    const float* __restrict__ S, float* __restrict__ out)
{
    const int blk  = blockIdx.x;
    const int t    = threadIdx.x;
    const int lane = t & 63, wave = t >> 6;   // 16 waves
    const int b    = blk >> 5, slab = blk & 31;

    __shared__ float smem[CH];
    if (t < 256)
        reinterpret_cast<float4*>(smem)[t] =
            reinterpret_cast<const float4*>(S + (size_t)b * CH)[t];
    __syncthreads();

    const int d0 = slab * 32 + wave * 2;
    const float4* s4 = reinterpret_cast<const float4*>(smem);
    #pragma unroll
    for (int j = 0; j < 2; j++) {
        const int d = d0 + j;
        const float4* wrow = reinterpret_cast<const float4*>(Wo + (size_t)d * CH);
        float a = 0.f;
        #pragma unroll
        for (int i = 0; i < 4; i++) {
            int e4 = i * 64 + lane;
            float4 w = wrow[e4];
            float4 c = s4[e4];
            a += w.x * c.x + w.y * c.y + w.z * c.z + w.w * c.w;
        }
        #pragma unroll
        for (int m = 1; m < 64; m <<= 1) a += __shfl_xor(a, m);  // all lanes hold sum
        const float val = a + bo[d];
        float4 v4 = make_float4(val, val, val, val);
        float4* op = reinterpret_cast<float4*>(out + ((size_t)b * CH + d) * NHW);
        #pragma unroll
        for (int i = 0; i < 4; i++) op[i * 64 + lane] = v4;  // 1 KiB contiguous per wave-store
    }
}

extern "C" void kernel_launch(void* const* d_in, const int* in_sizes, int n_in,
                              void* d_out, int out_size, void* d_ws, size_t ws_size,
                              hipStream_t stream)
{
    const float* x     = (const float*)d_in[0];
    const float* gamma = (const float*)d_in[1];
    const float* beta  = (const float*)d_in[2];
    // d_in[3..6] = Wq, bq, Wk, bk: provably dead (softmax row-sum == 1)
    const float* Wv    = (const float*)d_in[7];
    const float* bv    = (const float*)d_in[8];
    const float* Wo    = (const float*)d_in[9];
    const float* bo    = (const float*)d_in[10];
    float* out = (float*)d_out;

    char* ws = (char*)d_ws;
    float* pbg  = (float*)ws;                         // 16*32*1024 f = 2 MiB
    float* Sbuf = (float*)(ws + (size_t)2 * 1024 * 1024);  // 16*1024 f = 64 KiB

    // No memset, no atomics: partials are plain-stored, reduced in K2.
    k1_partials     <<<BATCH * G, 1024, 0, stream>>>(x, gamma, beta, pbg);
    k2_reduce_matvec<<<BATCH * 8, 1024, 0, stream>>>(pbg, Wv, bv, Sbuf);
    k3_out          <<<BATCH * G, 1024, 0, stream>>>(Wo, bo, Sbuf, out);
}

// Round 12
// 160.733 us; speedup vs baseline: 1.0253x; 1.0253x over previous
//
#include <hip/hip_runtime.h>

// Reference collapses: softmax row-sums are exactly 1, and einsum 'bqk,bvd->bqd'
// contracts k and v independently, so out[b,q,d] = sum_n v[b,n,d] (q-independent).
//   colsum[b,ch] = sum_n GN(x)[b,n,ch]   (K1: block-local stats + atomics)
//   S[b,d]       = dot(Wv[d,:], colsum[b,:]) + 1024*bv[d]          (K2)
//   out[b,d,:]   = dot(Wo[d,:], S[b,:]) + bo[d]  broadcast over hw (K3)
// Wq/bq/Wk/bk are provably dead (softmax row-sum == 1).
//
// Round 12: restore round 8 verbatim — the equal-best measured config
// (158.0us; tied with the fused+software-barrier variant at 158.1us).
// R10/R11 A/B proved the atomic-free partials/reduce structure is ~7us
// SLOWER than this atomics version (store-reduce round trip + cross-XCD
// partial reads cost more than the TCC-side atomic tail), and nt-stores
// are perf-neutral. Measured landscape: fusion, software barriers, TLP
// 8->16->32 waves/CU, contiguous-read repartition, atomic-free reduce,
// nt-stores — all converge to ~158 or regress. This is the keeper.

#define BATCH 16
#define CH    1024
#define NHW   1024
#define G     32
#define NPG   32
#define EPG   (NPG*CH)
#define EPSV  1e-5f

// ---- K1: GN stats + colsum contribution; block (b,g) owns group (b,g) ----
__global__ __launch_bounds__(1024, 8) void k1_stats_colsum(
    const float* __restrict__ x, const float* __restrict__ gamma,
    const float* __restrict__ beta, float* __restrict__ colsum)
{
    const int blk  = blockIdx.x;
    const int t    = threadIdx.x;
    const int lane = t & 63, wave = t >> 6;   // 16 waves
    const int b    = blk >> 5, g = blk & 31;
    const int n4   = t & 7;                   // which float4 of the group's 32 n's
    const int c0   = t >> 3;                  // starting channel 0..127

    __shared__ float pch[CH];                 // gamma-weighted per-channel partials
    __shared__ float r1[16], r2[16], rb[16];

    const float4* xg = reinterpret_cast<const float4*>(x + (size_t)b * (CH * NHW) + g * NPG);
    const float4  gm = reinterpret_cast<const float4*>(gamma + g * NPG)[n4];

    float4 vb[8];
    #pragma unroll
    for (int k = 0; k < 8; k++)               // 8 independent loads in flight
        vb[k] = xg[(c0 + k * 128) * (NHW / 4) + n4];

    float s1 = 0.f, s2 = 0.f;
    #pragma unroll
    for (int k = 0; k < 8; k++) {
        const float4 v = vb[k];
        const int ch = c0 + k * 128;
        s1 += v.x + v.y + v.z + v.w;
        s2 += v.x * v.x + v.y * v.y + v.z * v.z + v.w * v.w;
        float p = v.x * gm.x + v.y * gm.y + v.z * gm.z + v.w * gm.w;
        p += __shfl_xor(p, 1);
        p += __shfl_xor(p, 2);
        p += __shfl_xor(p, 4);
        if (n4 == 0) pch[ch] = p;             // one writer per 8-lane cluster
    }
    float bsum = beta[t];                     // 1024 threads cover beta exactly
    #pragma unroll
    for (int m = 1; m < 64; m <<= 1) {
        s1 += __shfl_xor(s1, m); s2 += __shfl_xor(s2, m); bsum += __shfl_xor(bsum, m);
    }
    if (lane == 0) { r1[wave] = s1; r2[wave] = s2; rb[wave] = bsum; }
    __syncthreads();

    float S1 = 0.f, S2 = 0.f, SB = 0.f;
    #pragma unroll
    for (int w = 0; w < 16; w++) { S1 += r1[w]; S2 += r2[w]; SB += rb[w]; }
    const float mean = S1 * (1.f / EPG);
    const float var  = S2 * (1.f / EPG) - mean * mean;
    const float inv  = rsqrtf(var + EPSV);
    float sg = gm.x + gm.y + gm.z + gm.w;     // this group's 32 gammas
    sg += __shfl_xor(sg, 1);
    sg += __shfl_xor(sg, 2);
    sg += __shfl_xor(sg, 4);
    const float cshare = SB * (1.f / 32.f) - inv * mean * sg;

    atomicAdd(&colsum[b * CH + t], inv * pch[t] + cshare);  // one per thread
}

// ---- K2: S[b,d] = dot(Wv[d,:], colsum[b,:]) + 1024*bv[d]; one wave per d ----
__global__ __launch_bounds__(256) void k2_matvec_v(
    const float* __restrict__ Wv, const float* __restrict__ bv,
    const float* __restrict__ colsum, float* __restrict__ S)
{
    const int t = threadIdx.x;
    const int wave = t >> 6, lane = t & 63;
    const int d = blockIdx.x * 4 + wave;      // 256 blocks * 4 waves = 1024 rows
    const float4* wrow = reinterpret_cast<const float4*>(Wv + (size_t)d * CH);
    const float4* cs4  = reinterpret_cast<const float4*>(colsum);
    float acc[BATCH];
    #pragma unroll
    for (int b = 0; b < BATCH; b++) acc[b] = 0.f;
    #pragma unroll
    for (int i = 0; i < 4; i++) {
        int e4 = i * 64 + lane;
        float4 w = wrow[e4];
        #pragma unroll
        for (int b = 0; b < BATCH; b++) {
            float4 c = cs4[b * 256 + e4];
            acc[b] += w.x * c.x + w.y * c.y + w.z * c.z + w.w * c.w;
        }
    }
    #pragma unroll
    for (int b = 0; b < BATCH; b++) {
        float a = acc[b];
        #pragma unroll
        for (int m = 1; m < 64; m <<= 1) a += __shfl_xor(a, m);
        if (lane == 0) S[b * CH + d] = a + (float)NHW * bv[d];
    }
}

// ---- K3: out[b,d,:] = dot(Wo[d,:], S[b,:]) + bo[d], bcast over 1024 hw ----
// 512 blocks (b, slab) x 16 waves; wave computes 2 rows; S[b,:] staged in LDS.
__global__ __launch_bounds__(1024, 8) void k3_out(
    const float* __restrict__ Wo, const float* __restrict__ bo,
    const float* __restrict__ S, float* __restrict__ out)
{
    const int blk  = blockIdx.x;
    const int t    = threadIdx.x;
    const int lane = t & 63, wave = t >> 6;   // 16 waves
    const int b    = blk >> 5, slab = blk & 31;

    __shared__ float smem[CH];
    if (t < 256)
        reinterpret_cast<float4*>(smem)[t] =
            reinterpret_cast<const float4*>(S + (size_t)b * CH)[t];
    __syncthreads();

    const int d0 = slab * 32 + wave * 2;
    const float4* s4 = reinterpret_cast<const float4*>(smem);
    #pragma unroll
    for (int j = 0; j < 2; j++) {
        const int d = d0 + j;
        const float4* wrow = reinterpret_cast<const float4*>(Wo + (size_t)d * CH);
        float a = 0.f;
        #pragma unroll
        for (int i = 0; i < 4; i++) {
            int e4 = i * 64 + lane;
            float4 w = wrow[e4];
            float4 c = s4[e4];
            a += w.x * c.x + w.y * c.y + w.z * c.z + w.w * c.w;
        }
        #pragma unroll
        for (int m = 1; m < 64; m <<= 1) a += __shfl_xor(a, m);  // all lanes hold sum
        const float val = a + bo[d];
        float4 v4 = make_float4(val, val, val, val);
        float4* op = reinterpret_cast<float4*>(out + ((size_t)b * CH + d) * NHW);
        #pragma unroll
        for (int i = 0; i < 4; i++) op[i * 64 + lane] = v4;  // 1 KiB contiguous per wave-store
    }
}

extern "C" void kernel_launch(void* const* d_in, const int* in_sizes, int n_in,
                              void* d_out, int out_size, void* d_ws, size_t ws_size,
                              hipStream_t stream)
{
    const float* x     = (const float*)d_in[0];
    const float* gamma = (const float*)d_in[1];
    const float* beta  = (const float*)d_in[2];
    // d_in[3..6] = Wq, bq, Wk, bk: provably dead (softmax row-sum == 1)
    const float* Wv    = (const float*)d_in[7];
    const float* bv    = (const float*)d_in[8];
    const float* Wo    = (const float*)d_in[9];
    const float* bo    = (const float*)d_in[10];
    float* out = (float*)d_out;

    char* ws = (char*)d_ws;
    float* colsum = (float*)ws;                       // 16*1024 f = 64 KiB
    float* Sbuf   = (float*)(ws + 65536);             // 16*1024 f = 64 KiB

    hipMemsetAsync(colsum, 0, BATCH * CH * sizeof(float), stream);
    k1_stats_colsum<<<BATCH * G, 1024, 0, stream>>>(x, gamma, beta, colsum);
    k2_matvec_v    <<<256,       256, 0, stream>>>(Wv, bv, colsum, Sbuf);
    k3_out         <<<BATCH * G, 1024, 0, stream>>>(Wo, bo, Sbuf, out);
}